// Round 6
// baseline (202.025 us; speedup 1.0000x reference)
//
#include <hip/hip_runtime.h>

// x [B=16, N=1024, F=256] fp32.  Algebra:
//   U2 = x@(Wr@Wu)^T + Wr@bu
//   M2t[b][j][k] = sum_i U2[b,i,j] * beta[b,i,k]
//   out[m,j] = (alpha[m,:].M2t[b][j,:] - d[m]*U2[m,j]) / N + x[m,j]
// K1 prep : Wcb = bf16(Wr@Wu); bc = Wr@bu
// K2 proj3: BM=64 BK=64, grid 1024 (4 blk/CU): {alpha,U2} + {betaT,U2T} + dpart
// K3 m2   : split-K x4, BK=64, grid 1024: fp32 partials
// K4 mred : reduce partials -> bf16 M2t
// K5 final: BM=64 BK=64, grid 1024: out fp32

typedef __bf16 bf16;
typedef float floatx4 __attribute__((ext_vector_type(4)));
typedef bf16 bf16x8 __attribute__((ext_vector_type(8)));
typedef bf16 bf16x4 __attribute__((ext_vector_type(4)));

constexpr int FD = 256;
constexpr int NB = 16;
constexpr int NN = 1024;
constexpr int RR = NB * NN;   // 16384

__device__ __forceinline__ bf16x8 cvt8(float4 a, float4 b) {
    bf16x8 o = { (bf16)a.x, (bf16)a.y, (bf16)a.z, (bf16)a.w,
                 (bf16)b.x, (bf16)b.y, (bf16)b.z, (bf16)b.w };
    return o;
}

// ---------------- K1: prep ----------------
__global__ __launch_bounds__(256)
void prep(const float* __restrict__ Wu, const float* __restrict__ bu, const float* __restrict__ Wr,
          bf16* __restrict__ Wcb, float* __restrict__ bc)
{
    const int blk = blockIdx.x, tid = threadIdx.x;
    if (blk < 256) {
        const int j = blk;
        float acc = 0.0f;
        for (int g = 0; g < FD; g += 4) {
            float4 wr = *(const float4*)&Wr[j * FD + g];
            acc += wr.x * Wu[g * FD + tid] + wr.y * Wu[(g + 1) * FD + tid]
                 + wr.z * Wu[(g + 2) * FD + tid] + wr.w * Wu[(g + 3) * FD + tid];
        }
        Wcb[j * FD + tid] = (bf16)acc;
    } else {
        float s = 0.0f;
        for (int g = 0; g < FD; g++) s += Wr[tid * FD + g] * bu[g];
        bc[tid] = s;
    }
}

// ---------------- K2: proj3  (BM=64, BN=64, BK=64) ----------------
__global__ __launch_bounds__(256)
void proj3(const float* __restrict__ x,
           const float* __restrict__ Wa, const float* __restrict__ Wb, const bf16* __restrict__ Wc,
           bf16* __restrict__ alpha, bf16* __restrict__ U2,
           bf16* __restrict__ betaT, bf16* __restrict__ U2T,
           const float* __restrict__ bc, float* __restrict__ dpart)
{
    constexpr int LDK = 68, WSZ = 64 * LDK;          // 4352 bf16 per matrix
    __shared__ __align__(16) bf16 smem[4 * WSZ];     // As | Bs0 Bs1 Bs2 ; Tr aliases front
    bf16* As = smem;
    bf16* Bs = smem + WSZ;
    bf16* Tr = smem;                                 // used after K-loop only
    const int tid = threadIdx.x;
    const int wave = tid >> 6, lane = tid & 63;
    const int q = lane >> 4, l16 = lane & 15;
    const int bm = blockIdx.y * 64, bn = blockIdx.x * 64;

    const int row0 = tid >> 3, k8 = (tid & 7) * 8;   // rows 0..31
    // second chunk: row0+32, same k8

    bf16x8 pA[2], pW0[2], pW1[2]; int4 pW2[2];
#define PROJ_LOAD(KK) do { \
        const float* s0 = &x[(size_t)(bm + row0) * FD + (KK) + k8]; \
        pA[0] = cvt8(*(const float4*)s0, *(const float4*)(s0 + 4)); \
        const float* s1 = &x[(size_t)(bm + row0 + 32) * FD + (KK) + k8]; \
        pA[1] = cvt8(*(const float4*)s1, *(const float4*)(s1 + 4)); \
        const float* a0 = &Wa[(size_t)(bn + row0) * FD + (KK) + k8]; \
        pW0[0] = cvt8(*(const float4*)a0, *(const float4*)(a0 + 4)); \
        const float* a1 = &Wa[(size_t)(bn + row0 + 32) * FD + (KK) + k8]; \
        pW0[1] = cvt8(*(const float4*)a1, *(const float4*)(a1 + 4)); \
        const float* b0 = &Wb[(size_t)(bn + row0) * FD + (KK) + k8]; \
        pW1[0] = cvt8(*(const float4*)b0, *(const float4*)(b0 + 4)); \
        const float* b1 = &Wb[(size_t)(bn + row0 + 32) * FD + (KK) + k8]; \
        pW1[1] = cvt8(*(const float4*)b1, *(const float4*)(b1 + 4)); \
        pW2[0] = *(const int4*)&Wc[(size_t)(bn + row0) * FD + (KK) + k8]; \
        pW2[1] = *(const int4*)&Wc[(size_t)(bn + row0 + 32) * FD + (KK) + k8]; \
    } while (0)

    floatx4 acc[3][4] = {};
    PROJ_LOAD(0);

    for (int k0 = 0; k0 < FD; k0 += 64) {
        *(bf16x8*)&As[row0 * LDK + k8] = pA[0];
        *(bf16x8*)&As[(row0 + 32) * LDK + k8] = pA[1];
        *(bf16x8*)&Bs[0 * WSZ + row0 * LDK + k8] = pW0[0];
        *(bf16x8*)&Bs[0 * WSZ + (row0 + 32) * LDK + k8] = pW0[1];
        *(bf16x8*)&Bs[1 * WSZ + row0 * LDK + k8] = pW1[0];
        *(bf16x8*)&Bs[1 * WSZ + (row0 + 32) * LDK + k8] = pW1[1];
        *(int4*)&Bs[2 * WSZ + row0 * LDK + k8] = pW2[0];
        *(int4*)&Bs[2 * WSZ + (row0 + 32) * LDK + k8] = pW2[1];
        __syncthreads();
        if (k0 + 64 < FD) PROJ_LOAD(k0 + 64);
        bf16x8 af[2];
        #pragma unroll
        for (int h = 0; h < 2; h++)
            af[h] = *(const bf16x8*)&As[(wave * 16 + l16) * LDK + h * 32 + q * 8];
        #pragma unroll
        for (int w = 0; w < 3; w++) {
            #pragma unroll
            for (int h = 0; h < 2; h++) {
                #pragma unroll
                for (int nj = 0; nj < 4; nj++) {
                    bf16x8 bq = *(const bf16x8*)&Bs[w * WSZ + (nj * 16 + l16) * LDK + h * 32 + q * 8];
                    acc[w][nj] = __builtin_amdgcn_mfma_f32_16x16x32_bf16(af[h], bq, acc[w][nj], 0, 0, 0);
                }
            }
        }
        __syncthreads();
    }
#undef PROJ_LOAD

    const int b = bm >> 10, n0 = bm & (NN - 1);
    float bcv[4];
    #pragma unroll
    for (int nj = 0; nj < 4; nj++) bcv[nj] = bc[bn + nj * 16 + l16];

    // diag partials
    #pragma unroll
    for (int i = 0; i < 4; i++) {
        float p = 0.0f;
        #pragma unroll
        for (int nj = 0; nj < 4; nj++)
            p += acc[0][nj][i] * acc[1][nj][i];
        #pragma unroll
        for (int off = 1; off < 16; off <<= 1) p += __shfl_xor(p, off);
        if (l16 == 0) {
            int m = bm + wave * 16 + q * 4 + i;
            dpart[(size_t)blockIdx.x * RR + m] = p;
        }
    }

    // natural outputs: alpha (w=0), U2 (w=2 +bc); repack [64][68]
    #pragma unroll
    for (int pass = 0; pass < 2; pass++) {
        const int w = pass ? 2 : 0;
        __syncthreads();
        #pragma unroll
        for (int i = 0; i < 4; i++) {
            int ml = wave * 16 + q * 4 + i;
            #pragma unroll
            for (int nj = 0; nj < 4; nj++) {
                float v = acc[w][nj][i];
                if (w == 2) v += bcv[nj];
                Tr[ml * 68 + nj * 16 + l16] = (bf16)v;
            }
        }
        __syncthreads();
        bf16* dst = pass ? U2 : alpha;
        #pragma unroll
        for (int it = 0; it < 2; it++) {
            int c = tid + it * 256;
            int row = c >> 3, chunk = c & 7;
            bf16x8 v = *(const bf16x8*)&Tr[row * 68 + chunk * 8];
            *(bf16x8*)&dst[(size_t)(bm + row) * FD + bn + chunk * 8] = v;
        }
    }

    // transposed outputs: betaT (w=1), U2T (w=2 +bc); repack [64][72]
    #pragma unroll
    for (int pass = 0; pass < 2; pass++) {
        const int w = pass ? 2 : 1;
        __syncthreads();
        #pragma unroll
        for (int nj = 0; nj < 4; nj++) {
            bf16x4 v4;
            #pragma unroll
            for (int i = 0; i < 4; i++) {
                float v = acc[w][nj][i];
                if (w == 2) v += bcv[nj];
                v4[i] = (bf16)v;
            }
            *(bf16x4*)&Tr[(nj * 16 + l16) * 72 + wave * 16 + q * 4] = v4;
        }
        __syncthreads();
        bf16* dst = (pass ? U2T : betaT) + (size_t)b * FD * NN;
        #pragma unroll
        for (int it = 0; it < 2; it++) {
            int c = tid + it * 256;
            int row = c >> 3, chunk = c & 7;
            bf16x8 v = *(const bf16x8*)&Tr[row * 72 + chunk * 8];
            *(bf16x8*)&dst[(size_t)(bn + row) * NN + n0 + chunk * 8] = v;
        }
    }
}

// ---------------- K3: m2 split-K: Mpart[ch][b][j][k] = sum_{n in chunk} U2T[j,n]*betaT[k,n] ----------------
__global__ __launch_bounds__(256)
void m2_mfma(const bf16* __restrict__ U2T, const bf16* __restrict__ betaT, float* __restrict__ Mpart)
{
    constexpr int LDK = 68;
    __shared__ __align__(16) bf16 As[64 * LDK];
    __shared__ __align__(16) bf16 Bs[64 * LDK];
    const int tid = threadIdx.x;
    const int wave = tid >> 6, lane = tid & 63;
    const int q = lane >> 4, l16 = lane & 15;
    const int wj = wave >> 1, wk = wave & 1;
    const int b = blockIdx.z >> 2, ch = blockIdx.z & 3;
    const int bj = blockIdx.y * 64, bk = blockIdx.x * 64;
    const int nb = ch * 256;
    const int row0 = tid >> 3, k8 = (tid & 7) * 8;
    const bf16* Ap = U2T + (size_t)b * FD * NN;
    const bf16* Bp = betaT + (size_t)b * FD * NN;

    int4 ra[2], rb[2];
    ra[0] = *(const int4*)&Ap[(size_t)(bj + row0) * NN + nb + k8];
    ra[1] = *(const int4*)&Ap[(size_t)(bj + row0 + 32) * NN + nb + k8];
    rb[0] = *(const int4*)&Bp[(size_t)(bk + row0) * NN + nb + k8];
    rb[1] = *(const int4*)&Bp[(size_t)(bk + row0 + 32) * NN + nb + k8];

    floatx4 acc[2][2] = {};
    for (int nc = 0; nc < 256; nc += 64) {
        *(int4*)&As[row0 * LDK + k8] = ra[0];
        *(int4*)&As[(row0 + 32) * LDK + k8] = ra[1];
        *(int4*)&Bs[row0 * LDK + k8] = rb[0];
        *(int4*)&Bs[(row0 + 32) * LDK + k8] = rb[1];
        __syncthreads();
        if (nc + 64 < 256) {
            int nn = nb + nc + 64;
            ra[0] = *(const int4*)&Ap[(size_t)(bj + row0) * NN + nn + k8];
            ra[1] = *(const int4*)&Ap[(size_t)(bj + row0 + 32) * NN + nn + k8];
            rb[0] = *(const int4*)&Bp[(size_t)(bk + row0) * NN + nn + k8];
            rb[1] = *(const int4*)&Bp[(size_t)(bk + row0 + 32) * NN + nn + k8];
        }
        #pragma unroll
        for (int h = 0; h < 2; h++) {
            bf16x8 af[2], bq[2];
            #pragma unroll
            for (int mi = 0; mi < 2; mi++)
                af[mi] = *(const bf16x8*)&As[(wj * 32 + mi * 16 + l16) * LDK + h * 32 + q * 8];
            #pragma unroll
            for (int kj = 0; kj < 2; kj++)
                bq[kj] = *(const bf16x8*)&Bs[(wk * 32 + kj * 16 + l16) * LDK + h * 32 + q * 8];
            #pragma unroll
            for (int mi = 0; mi < 2; mi++)
                #pragma unroll
                for (int kj = 0; kj < 2; kj++)
                    acc[mi][kj] = __builtin_amdgcn_mfma_f32_16x16x32_bf16(af[mi], bq[kj], acc[mi][kj], 0, 0, 0);
        }
        __syncthreads();
    }

    float* P = Mpart + ((size_t)ch * NB + b) * FD * FD;
    #pragma unroll
    for (int mi = 0; mi < 2; mi++)
        #pragma unroll
        for (int i = 0; i < 4; i++) {
            int j = bj + wj * 32 + mi * 16 + q * 4 + i;
            #pragma unroll
            for (int kj = 0; kj < 2; kj++)
                P[(size_t)j * FD + bk + wk * 32 + kj * 16 + l16] = acc[mi][kj][i];
        }
}

// ---------------- K4: mred — reduce 4 fp32 partials -> bf16 M2t ----------------
__global__ __launch_bounds__(256)
void mred(const float* __restrict__ Mpart, bf16* __restrict__ M2t)
{
    const size_t S = (size_t)NB * FD * FD;
    size_t i = ((size_t)blockIdx.x * 256 + threadIdx.x) * 8;
    float4 a0 = *(const float4*)&Mpart[i],         a1 = *(const float4*)&Mpart[i + 4];
    float4 b0 = *(const float4*)&Mpart[S + i],     b1 = *(const float4*)&Mpart[S + i + 4];
    float4 c0 = *(const float4*)&Mpart[2*S + i],   c1 = *(const float4*)&Mpart[2*S + i + 4];
    float4 d0 = *(const float4*)&Mpart[3*S + i],   d1 = *(const float4*)&Mpart[3*S + i + 4];
    bf16x8 o = { (bf16)(a0.x + b0.x + c0.x + d0.x), (bf16)(a0.y + b0.y + c0.y + d0.y),
                 (bf16)(a0.z + b0.z + c0.z + d0.z), (bf16)(a0.w + b0.w + c0.w + d0.w),
                 (bf16)(a1.x + b1.x + c1.x + d1.x), (bf16)(a1.y + b1.y + c1.y + d1.y),
                 (bf16)(a1.z + b1.z + c1.z + d1.z), (bf16)(a1.w + b1.w + c1.w + d1.w) };
    *(bf16x8*)&M2t[i] = o;
}

// ---------------- K5: final (BM=64, BN=64, BK=64) ----------------
__global__ __launch_bounds__(256)
void final_mfma(const bf16* __restrict__ alpha, const bf16* __restrict__ M2t,
                const float* __restrict__ dpart, const bf16* __restrict__ U2,
                const float* __restrict__ x, float* __restrict__ out)
{
    constexpr int LDK = 68;
    __shared__ __align__(16) bf16 As[64 * LDK];
    __shared__ __align__(16) bf16 Bs[64 * LDK];
    const int tid = threadIdx.x;
    const int wave = tid >> 6, lane = tid & 63;
    const int q = lane >> 4, l16 = lane & 15;
    const int bm = blockIdx.y * 64, bn = blockIdx.x * 64;
    const bf16* Qb = M2t + (size_t)(bm >> 10) * FD * FD;
    const int row0 = tid >> 3, k8 = (tid & 7) * 8;

    int4 ra[2], rb[2];
    ra[0] = *(const int4*)&alpha[(size_t)(bm + row0) * FD + k8];
    ra[1] = *(const int4*)&alpha[(size_t)(bm + row0 + 32) * FD + k8];
    rb[0] = *(const int4*)&Qb[(size_t)(bn + row0) * FD + k8];
    rb[1] = *(const int4*)&Qb[(size_t)(bn + row0 + 32) * FD + k8];

    floatx4 acc[4] = {};
    for (int k0 = 0; k0 < FD; k0 += 64) {
        *(int4*)&As[row0 * LDK + k8] = ra[0];
        *(int4*)&As[(row0 + 32) * LDK + k8] = ra[1];
        *(int4*)&Bs[row0 * LDK + k8] = rb[0];
        *(int4*)&Bs[(row0 + 32) * LDK + k8] = rb[1];
        __syncthreads();
        if (k0 + 64 < FD) {
            ra[0] = *(const int4*)&alpha[(size_t)(bm + row0) * FD + k0 + 64 + k8];
            ra[1] = *(const int4*)&alpha[(size_t)(bm + row0 + 32) * FD + k0 + 64 + k8];
            rb[0] = *(const int4*)&Qb[(size_t)(bn + row0) * FD + k0 + 64 + k8];
            rb[1] = *(const int4*)&Qb[(size_t)(bn + row0 + 32) * FD + k0 + 64 + k8];
        }
        #pragma unroll
        for (int h = 0; h < 2; h++) {
            bf16x8 af = *(const bf16x8*)&As[(wave * 16 + l16) * LDK + h * 32 + q * 8];
            #pragma unroll
            for (int nj = 0; nj < 4; nj++) {
                bf16x8 bq = *(const bf16x8*)&Bs[(nj * 16 + l16) * LDK + h * 32 + q * 8];
                acc[nj] = __builtin_amdgcn_mfma_f32_16x16x32_bf16(af, bq, acc[nj], 0, 0, 0);
            }
        }
        __syncthreads();
    }

    #pragma unroll
    for (int i = 0; i < 4; i++) {
        int m = bm + wave * 16 + q * 4 + i;
        float d = dpart[m] + dpart[RR + m] + dpart[2 * RR + m] + dpart[3 * RR + m];
        #pragma unroll
        for (int nj = 0; nj < 4; nj++) {
            int n = bn + nj * 16 + l16;
            float v = (acc[nj][i] - d * (float)U2[(size_t)m * FD + n]) * (1.0f / 1024.0f);
            out[(size_t)m * FD + n] = v + x[(size_t)m * FD + n];
        }
    }
}

extern "C" void kernel_launch(void* const* d_in, const int* in_sizes, int n_in,
                              void* d_out, int out_size, void* d_ws, size_t ws_size,
                              hipStream_t stream)
{
    const float* x  = (const float*)d_in[0];
    const float* Wa = (const float*)d_in[1];
    const float* Wb = (const float*)d_in[2];
    const float* Wu = (const float*)d_in[3];
    const float* bu = (const float*)d_in[4];
    const float* Wr = (const float*)d_in[5];
    float* out = (float*)d_out;

    char* w = (char*)d_ws;
    bf16* Wcb   = (bf16*)w;  w += (size_t)FD * FD * 2;
    float* bc   = (float*)w; w += (size_t)FD * 4;
    bf16* alpha = (bf16*)w;  w += (size_t)RR * FD * 2;
    bf16* U2    = (bf16*)w;  w += (size_t)RR * FD * 2;
    bf16* betaT = (bf16*)w;  w += (size_t)RR * FD * 2;
    bf16* U2T   = (bf16*)w;  w += (size_t)RR * FD * 2;
    bf16* M2t   = (bf16*)w;  w += (size_t)NB * FD * FD * 2;
    float* dpart= (float*)w; w += (size_t)4 * RR * 4;
    float* Mpart= (float*)w; w += (size_t)4 * NB * FD * FD * 4;   // 16 MB

    dim3 blk(256);

    prep<<<dim3(257), blk, 0, stream>>>(Wu, bu, Wr, Wcb, bc);

    proj3<<<dim3(FD / 64, RR / 64), blk, 0, stream>>>(x, Wa, Wb, Wcb,
                                                      alpha, U2, betaT, U2T, bc, dpart);

    m2_mfma<<<dim3(FD / 64, FD / 64, NB * 4), blk, 0, stream>>>(U2T, betaT, Mpart);

    mred<<<dim3(512), blk, 0, stream>>>(Mpart, M2t);

    final_mfma<<<dim3(FD / 64, RR / 64), blk, 0, stream>>>(alpha, M2t, dpart, U2, x, out);
}

// Round 7
// 128.667 us; speedup vs baseline: 1.5701x; 1.5701x over previous
//
#include <hip/hip_runtime.h>

// x [B=16, N=1024, F=256] fp32.  Algebra:
//   U2 = x@(Wr@Wu)^T + Wr@bu
//   M2t[b][j][k] = sum_i U2[b,i,j] * beta[b,i,k]
//   out[m,j] = (alpha[m,:].M2t[b][j,:] - d[m]*U2[m,j]) / N + x[m,j]
// K1 prep : xb,Wab,Wbb = bf16(x,Wa,Wb); Wcb = bf16(Wr@Wu); bc = Wr@bu
// K2 proj3: R4 structure (BM=128,BK=32,LDK=36), all-bf16 operands
// K3 m2   : M2t = U2T @ betaT^T (NT, K=1024), packed stores   [R4]
// K4 final: out fp32                                           [R4]

typedef __bf16 bf16;
typedef float floatx4 __attribute__((ext_vector_type(4)));
typedef bf16 bf16x8 __attribute__((ext_vector_type(8)));
typedef bf16 bf16x4 __attribute__((ext_vector_type(4)));

constexpr int FD = 256;
constexpr int NB = 16;
constexpr int NN = 1024;
constexpr int RR = NB * NN;   // 16384

// ---------------- K1: prep ----------------
// grid: [0,2048) x cvt | [2048,2064) Wa/Wb cvt | [2064,2320) Wc | 2320 bc
__global__ __launch_bounds__(256)
void prep(const float* __restrict__ x, const float* __restrict__ Wa, const float* __restrict__ Wb,
          const float* __restrict__ Wu, const float* __restrict__ bu, const float* __restrict__ Wr,
          bf16* __restrict__ xb, bf16* __restrict__ Wab, bf16* __restrict__ Wbb,
          bf16* __restrict__ Wcb, float* __restrict__ bc)
{
    const int blk = blockIdx.x, tid = threadIdx.x;
    if (blk < 2048) {  // x -> bf16, 8 elems/thread
        size_t i = ((size_t)blk * 256 + tid) * 8;
        float4 v0 = *(const float4*)&x[i];
        float4 v1 = *(const float4*)&x[i + 4];
        bf16x8 o = { (bf16)v0.x, (bf16)v0.y, (bf16)v0.z, (bf16)v0.w,
                     (bf16)v1.x, (bf16)v1.y, (bf16)v1.z, (bf16)v1.w };
        *(bf16x8*)&xb[i] = o;
    } else if (blk < 2064) {  // Wa,Wb -> bf16: 2 weights x 8 blocks
        int rel = blk - 2048, w = rel >> 3, wb = rel & 7;
        const float* src = (w == 0) ? Wa : Wb;
        bf16* dst = (w == 0) ? Wab : Wbb;
        for (int it = 0; it < 8; it++) {
            int i = wb * 8192 + it * 1024 + tid * 4;
            float4 v = *(const float4*)&src[i];
            bf16x4 o = { (bf16)v.x, (bf16)v.y, (bf16)v.z, (bf16)v.w };
            *(bf16x4*)&dst[i] = o;
        }
    } else if (blk < 2320) {  // Wc[j][f] = sum_g Wr[j][g]*Wu[g][f]; one j per block
        const int j = blk - 2064;
        float acc = 0.0f;
        for (int g = 0; g < FD; g += 4) {
            float4 wr = *(const float4*)&Wr[j * FD + g];
            acc += wr.x * Wu[g * FD + tid] + wr.y * Wu[(g + 1) * FD + tid]
                 + wr.z * Wu[(g + 2) * FD + tid] + wr.w * Wu[(g + 3) * FD + tid];
        }
        Wcb[j * FD + tid] = (bf16)acc;
    } else {  // bc[j] = Wr[j,:].bu
        float s = 0.0f;
        for (int g = 0; g < FD; g++) s += Wr[tid * FD + g] * bu[g];
        bc[tid] = s;
    }
}

// ---------------- K2: proj3 (BM=128, BN=64, BK=32, all-bf16 operands) ----------------
__global__ __launch_bounds__(256)
void proj3(const bf16* __restrict__ xb,
           const bf16* __restrict__ Wab, const bf16* __restrict__ Wbb, const bf16* __restrict__ Wc,
           bf16* __restrict__ alpha, bf16* __restrict__ U2,
           bf16* __restrict__ betaT, bf16* __restrict__ U2T,
           const float* __restrict__ bc, float* __restrict__ dpart)
{
    constexpr int BM = 128, BN = 64, BK = 32, LDK = 36;
    __shared__ bf16 As[BM][LDK];
    __shared__ bf16 Bs[3][BN][LDK];
    __shared__ bf16 Tr[8960];   // union: natural [128][68] (8704) / transposed [64][140] (8960)
    const int tid = threadIdx.x;
    const int wave = tid >> 6, lane = tid & 63;
    const int q = lane >> 4, l16 = lane & 15;
    const int bm = blockIdx.y * BM, bn = blockIdx.x * BN;

    const int rowA0 = tid >> 2,          k8A0 = (tid & 3) * 8;
    const int rowA1 = (tid + 256) >> 2,  k8A1 = (tid & 3) * 8;
    const int rowW  = tid >> 2,          k8W  = (tid & 3) * 8;

    int4 pxa0, pxa1, pwa, pwb, pwc;
#define PROJ_LOAD(KK) do { \
        pxa0 = *(const int4*)&xb[(size_t)(bm + rowA0) * FD + (KK) + k8A0]; \
        pxa1 = *(const int4*)&xb[(size_t)(bm + rowA1) * FD + (KK) + k8A1]; \
        pwa  = *(const int4*)&Wab[(size_t)(bn + rowW) * FD + (KK) + k8W]; \
        pwb  = *(const int4*)&Wbb[(size_t)(bn + rowW) * FD + (KK) + k8W]; \
        pwc  = *(const int4*)&Wc[(size_t)(bn + rowW) * FD + (KK) + k8W]; \
    } while (0)

    floatx4 acc[3][2][4] = {};
    PROJ_LOAD(0);

    for (int k0 = 0; k0 < FD; k0 += BK) {
        *(int4*)&As[rowA0][k8A0] = pxa0;
        *(int4*)&As[rowA1][k8A1] = pxa1;
        *(int4*)&Bs[0][rowW][k8W] = pwa;
        *(int4*)&Bs[1][rowW][k8W] = pwb;
        *(int4*)&Bs[2][rowW][k8W] = pwc;
        __syncthreads();
        if (k0 + BK < FD) PROJ_LOAD(k0 + BK);
        bf16x8 af[2];
        #pragma unroll
        for (int mi = 0; mi < 2; mi++)
            af[mi] = *(const bf16x8*)&As[wave * 32 + mi * 16 + l16][q * 8];
        #pragma unroll
        for (int w = 0; w < 3; w++) {
            bf16x8 bq[4];
            #pragma unroll
            for (int nj = 0; nj < 4; nj++)
                bq[nj] = *(const bf16x8*)&Bs[w][nj * 16 + l16][q * 8];
            #pragma unroll
            for (int mi = 0; mi < 2; mi++)
                #pragma unroll
                for (int nj = 0; nj < 4; nj++)
                    acc[w][mi][nj] = __builtin_amdgcn_mfma_f32_16x16x32_bf16(af[mi], bq[nj], acc[w][mi][nj], 0, 0, 0);
        }
        __syncthreads();
    }
#undef PROJ_LOAD

    const int b = bm >> 10, n0 = bm & (NN - 1);
    float bcv[4];
    #pragma unroll
    for (int nj = 0; nj < 4; nj++) bcv[nj] = bc[bn + nj * 16 + l16];

    // diag partials
    #pragma unroll
    for (int mi = 0; mi < 2; mi++)
        #pragma unroll
        for (int i = 0; i < 4; i++) {
            float p = 0.0f;
            #pragma unroll
            for (int nj = 0; nj < 4; nj++)
                p += acc[0][mi][nj][i] * acc[1][mi][nj][i];
            #pragma unroll
            for (int off = 1; off < 16; off <<= 1) p += __shfl_xor(p, off);
            if (l16 == 0) {
                int m = bm + wave * 32 + mi * 16 + q * 4 + i;
                dpart[(size_t)blockIdx.x * RR + m] = p;
            }
        }

    // natural outputs via [128][68] repack: alpha (w=0), U2 (w=2 +bc)
    #pragma unroll
    for (int pass = 0; pass < 2; pass++) {
        const int w = pass ? 2 : 0;
        __syncthreads();
        #pragma unroll
        for (int mi = 0; mi < 2; mi++)
            #pragma unroll
            for (int i = 0; i < 4; i++) {
                int ml = wave * 32 + mi * 16 + q * 4 + i;
                #pragma unroll
                for (int nj = 0; nj < 4; nj++) {
                    float v = acc[w][mi][nj][i];
                    if (w == 2) v += bcv[nj];
                    Tr[ml * 68 + nj * 16 + l16] = (bf16)v;
                }
            }
        __syncthreads();
        bf16* dst = pass ? U2 : alpha;
        #pragma unroll
        for (int it = 0; it < 4; it++) {
            int c = tid + it * 256;
            int row = c >> 3, chunk = c & 7;
            bf16x8 v = *(const bf16x8*)&Tr[row * 68 + chunk * 8];
            *(bf16x8*)&dst[(size_t)(bm + row) * FD + bn + chunk * 8] = v;
        }
    }

    // transposed outputs via [64][140] repack: betaT (w=1), U2T (w=2 +bc)
    #pragma unroll
    for (int pass = 0; pass < 2; pass++) {
        const int w = pass ? 2 : 1;
        __syncthreads();
        #pragma unroll
        for (int mi = 0; mi < 2; mi++)
            #pragma unroll
            for (int nj = 0; nj < 4; nj++) {
                bf16x4 v4;
                #pragma unroll
                for (int i = 0; i < 4; i++) {
                    float v = acc[w][mi][nj][i];
                    if (w == 2) v += bcv[nj];
                    v4[i] = (bf16)v;
                }
                *(bf16x4*)&Tr[(nj * 16 + l16) * 140 + wave * 32 + mi * 16 + q * 4] = v4;
            }
        __syncthreads();
        bf16* dst = (pass ? U2T : betaT) + (size_t)b * FD * NN;
        #pragma unroll
        for (int it = 0; it < 4; it++) {
            int c = tid + it * 256;
            int row = c >> 4, chunk = c & 15;
            bf16x8 v = *(const bf16x8*)&Tr[row * 140 + chunk * 8];
            *(bf16x8*)&dst[(size_t)(bn + row) * NN + n0 + chunk * 8] = v;
        }
    }
}

// ---------------- K3: M2t[b][j][k] = sum_n U2T[b][j][n] * betaT[b][k][n] ----------------
__global__ __launch_bounds__(256)
void m2_mfma(const bf16* __restrict__ U2T, const bf16* __restrict__ betaT, bf16* __restrict__ M2t)
{
    constexpr int LDK = 36;
    __shared__ bf16 As[64][LDK];
    __shared__ bf16 Bs[64][LDK];
    __shared__ bf16 Tr[64 * 68];
    const int tid = threadIdx.x;
    const int wave = tid >> 6, lane = tid & 63;
    const int q = lane >> 4, l16 = lane & 15;
    const int wj = wave >> 1, wk = wave & 1;
    const int b = blockIdx.z;
    const int bj = blockIdx.y * 64, bk = blockIdx.x * 64;
    const int row = tid >> 2, k8 = (tid & 3) * 8;
    const bf16* Arow = U2T + (size_t)b * FD * NN + (size_t)(bj + row) * NN + k8;
    const bf16* Brow = betaT + (size_t)b * FD * NN + (size_t)(bk + row) * NN + k8;

    int4 ra = *(const int4*)&Arow[0];
    int4 rb = *(const int4*)&Brow[0];
    floatx4 acc[2][2] = {};
    for (int n0 = 0; n0 < NN; n0 += 32) {
        *(int4*)&As[row][k8] = ra;
        *(int4*)&Bs[row][k8] = rb;
        __syncthreads();
        if (n0 + 32 < NN) { ra = *(const int4*)&Arow[n0 + 32]; rb = *(const int4*)&Brow[n0 + 32]; }
        bf16x8 af[2], bq[2];
        #pragma unroll
        for (int mi = 0; mi < 2; mi++)
            af[mi] = *(const bf16x8*)&As[wj * 32 + mi * 16 + l16][q * 8];
        #pragma unroll
        for (int kj = 0; kj < 2; kj++)
            bq[kj] = *(const bf16x8*)&Bs[wk * 32 + kj * 16 + l16][q * 8];
        #pragma unroll
        for (int mi = 0; mi < 2; mi++)
            #pragma unroll
            for (int kj = 0; kj < 2; kj++)
                acc[mi][kj] = __builtin_amdgcn_mfma_f32_16x16x32_bf16(af[mi], bq[kj], acc[mi][kj], 0, 0, 0);
        __syncthreads();
    }
    __syncthreads();
    #pragma unroll
    for (int mi = 0; mi < 2; mi++)
        #pragma unroll
        for (int i = 0; i < 4; i++) {
            int jl = wj * 32 + mi * 16 + q * 4 + i;
            #pragma unroll
            for (int kj = 0; kj < 2; kj++)
                Tr[jl * 68 + wk * 32 + kj * 16 + l16] = (bf16)acc[mi][kj][i];
        }
    __syncthreads();
    bf16* Mb = M2t + (size_t)b * FD * FD;
    #pragma unroll
    for (int it = 0; it < 2; it++) {
        int c = tid + it * 256;
        int r = c >> 3, chunk = c & 7;
        bf16x8 v = *(const bf16x8*)&Tr[r * 68 + chunk * 8];
        *(bf16x8*)&Mb[(size_t)(bj + r) * FD + bk + chunk * 8] = v;
    }
}

// ---------------- K4: out = (alpha @ M2t[b]^T(NT) - d*U2)/N + x ----------------
__global__ __launch_bounds__(256)
void final_mfma(const bf16* __restrict__ alpha, const bf16* __restrict__ M2t,
                const float* __restrict__ dpart, const bf16* __restrict__ U2,
                const float* __restrict__ x, float* __restrict__ out)
{
    constexpr int BM = 128, BN = 64, BK = 32, LDK = 36;
    __shared__ bf16 As[BM][LDK];
    __shared__ bf16 Bs[BN][LDK];
    const int tid = threadIdx.x;
    const int wave = tid >> 6, lane = tid & 63;
    const int q = lane >> 4, l16 = lane & 15;
    const int bm = blockIdx.y * BM, bn = blockIdx.x * BN;
    const bf16* Qb = M2t + (size_t)(bm >> 10) * FD * FD;

    const int rowA0 = tid >> 2,         k8A0 = (tid & 3) * 8;
    const int rowA1 = (tid + 256) >> 2, k8A1 = (tid & 3) * 8;
    const int rowB  = tid >> 2,         k8B  = (tid & 3) * 8;

    int4 ra0 = *(const int4*)&alpha[(size_t)(bm + rowA0) * FD + k8A0];
    int4 ra1 = *(const int4*)&alpha[(size_t)(bm + rowA1) * FD + k8A1];
    int4 rb  = *(const int4*)&Qb[(size_t)(bn + rowB) * FD + k8B];

    floatx4 acc[2][4] = {};
    for (int k0 = 0; k0 < FD; k0 += BK) {
        *(int4*)&As[rowA0][k8A0] = ra0;
        *(int4*)&As[rowA1][k8A1] = ra1;
        *(int4*)&Bs[rowB][k8B] = rb;
        __syncthreads();
        if (k0 + BK < FD) {
            ra0 = *(const int4*)&alpha[(size_t)(bm + rowA0) * FD + k0 + BK + k8A0];
            ra1 = *(const int4*)&alpha[(size_t)(bm + rowA1) * FD + k0 + BK + k8A1];
            rb  = *(const int4*)&Qb[(size_t)(bn + rowB) * FD + k0 + BK + k8B];
        }
        bf16x8 af[2], bq[4];
        #pragma unroll
        for (int mi = 0; mi < 2; mi++)
            af[mi] = *(const bf16x8*)&As[wave * 32 + mi * 16 + l16][q * 8];
        #pragma unroll
        for (int nj = 0; nj < 4; nj++)
            bq[nj] = *(const bf16x8*)&Bs[nj * 16 + l16][q * 8];
        #pragma unroll
        for (int mi = 0; mi < 2; mi++)
            #pragma unroll
            for (int nj = 0; nj < 4; nj++)
                acc[mi][nj] = __builtin_amdgcn_mfma_f32_16x16x32_bf16(af[mi], bq[nj], acc[mi][nj], 0, 0, 0);
        __syncthreads();
    }

    #pragma unroll
    for (int mi = 0; mi < 2; mi++)
        #pragma unroll
        for (int i = 0; i < 4; i++) {
            int m = bm + wave * 32 + mi * 16 + q * 4 + i;
            float d = dpart[m] + dpart[RR + m] + dpart[2 * RR + m] + dpart[3 * RR + m];
            #pragma unroll
            for (int nj = 0; nj < 4; nj++) {
                int n = bn + nj * 16 + l16;
                float v = (acc[mi][nj][i] - d * (float)U2[(size_t)m * FD + n]) * (1.0f / 1024.0f);
                out[(size_t)m * FD + n] = v + x[(size_t)m * FD + n];
            }
        }
}

extern "C" void kernel_launch(void* const* d_in, const int* in_sizes, int n_in,
                              void* d_out, int out_size, void* d_ws, size_t ws_size,
                              hipStream_t stream)
{
    const float* x  = (const float*)d_in[0];
    const float* Wa = (const float*)d_in[1];
    const float* Wb = (const float*)d_in[2];
    const float* Wu = (const float*)d_in[3];
    const float* bu = (const float*)d_in[4];
    const float* Wr = (const float*)d_in[5];
    float* out = (float*)d_out;

    char* w = (char*)d_ws;
    bf16* xb    = (bf16*)w;  w += (size_t)RR * FD * 2;       // 8 MB
    bf16* Wab   = (bf16*)w;  w += (size_t)FD * FD * 2;
    bf16* Wbb   = (bf16*)w;  w += (size_t)FD * FD * 2;
    bf16* Wcb   = (bf16*)w;  w += (size_t)FD * FD * 2;
    float* bc   = (float*)w; w += (size_t)FD * 4;
    bf16* alpha = (bf16*)w;  w += (size_t)RR * FD * 2;
    bf16* U2    = (bf16*)w;  w += (size_t)RR * FD * 2;
    bf16* betaT = (bf16*)w;  w += (size_t)RR * FD * 2;
    bf16* U2T   = (bf16*)w;  w += (size_t)RR * FD * 2;
    bf16* M2t   = (bf16*)w;  w += (size_t)NB * FD * FD * 2;
    float* dpart= (float*)w; w += (size_t)4 * RR * 4;

    dim3 blk(256);

    prep<<<dim3(2321), blk, 0, stream>>>(x, Wa, Wb, Wu, bu, Wr, xb, Wab, Wbb, Wcb, bc);

    proj3<<<dim3(FD / 64, RR / 128), blk, 0, stream>>>(xb, Wab, Wbb, Wcb,
                                                       alpha, U2, betaT, U2T, bc, dpart);

    m2_mfma<<<dim3(FD / 64, FD / 64, NB), blk, 0, stream>>>(U2T, betaT, M2t);

    final_mfma<<<dim3(FD / 64, RR / 128), blk, 0, stream>>>(alpha, M2t, dpart, U2, x, out);
}